// Round 2
// baseline (373.297 us; speedup 1.0000x reference)
//
#include <hip/hip_runtime.h>
#include <math.h>

#define H 128

// One block per graph segment (batch sorted -> contiguous row ranges).
// 256 threads = 8 groups x 32 lanes. Each group processes 4 rows per
// iteration (4 independent float4 loads/lane -> 4KB/wave in flight) with a
// batched online-softmax update (1 rescale + 5 exps per 4 rows). Single
// pass over x fused with sum/max pooling, 8-way LDS merge, combine matmul.
__global__ __launch_bounds__(256, 4)
void pool_kernel(const float* __restrict__ x,
                 const int* __restrict__ batch,
                 const float* __restrict__ gate_w,
                 const float* __restrict__ gate_b,
                 const float* __restrict__ combine_w,
                 const float* __restrict__ combine_b,
                 float* __restrict__ out,
                 int N)
{
    const int g    = blockIdx.x;
    const int t    = threadIdx.x;
    const int grp  = t >> 5;   // 0..7
    const int lane = t & 31;   // feature block 4*lane

    __shared__ int   s_range[2];
    __shared__ float s_att[8][H];
    __shared__ float s_sum[8][H];
    __shared__ float s_mx[8][H];
    __shared__ float s_m[8], s_d[8];
    __shared__ float s_comb[3 * H];
    __shared__ float s_part[H];

    // --- segment bounds via binary search (batch sorted ascending) ---
    if (t < 2) {
        int target = g + t;
        int lo = 0, hi = N;
        while (lo < hi) {
            int mid = (lo + hi) >> 1;
            if (batch[mid] < target) lo = mid + 1; else hi = mid;
        }
        s_range[t] = lo;
    }
    __syncthreads();
    const int start = s_range[0];
    const int end   = s_range[1];
    const int cnt   = end - start;

    // per-lane gate weights (features 4*lane..4*lane+3)
    const float4 gw = ((const float4*)gate_w)[lane];
    const float  gb = gate_b[0];

    float  m = -INFINITY, d = 0.0f;
    float4 att = make_float4(0.f, 0.f, 0.f, 0.f);
    float4 sum = make_float4(0.f, 0.f, 0.f, 0.f);
    float4 mx  = make_float4(-INFINITY, -INFINITY, -INFINITY, -INFINITY);

    const float4* xv = (const float4*)x;  // row r, lane l -> xv[r*32 + l]

    // rows for this group in one iteration: base + grp + 8*i, i=0..3
    for (int base = start; base < end; base += 32) {
        const int r0 = base + grp;
        bool   valid[4];
        float4 xr[4];
        #pragma unroll
        for (int i = 0; i < 4; i++) {
            int r = r0 + 8 * i;
            valid[i] = (r < end);
            xr[i] = valid[i] ? xv[(size_t)r * 32 + lane]
                             : make_float4(0.f, 0.f, 0.f, 0.f);
        }

        // 4 gate dot-products, reduced across the 32-lane group (4 indep chains)
        float p[4];
        #pragma unroll
        for (int i = 0; i < 4; i++)
            p[i] = xr[i].x * gw.x + xr[i].y * gw.y + xr[i].z * gw.z + xr[i].w * gw.w;
        #pragma unroll
        for (int s = 1; s < 32; s <<= 1) {
            #pragma unroll
            for (int i = 0; i < 4; i++) p[i] += __shfl_xor(p[i], s);
        }
        float gv[4];
        #pragma unroll
        for (int i = 0; i < 4; i++)
            gv[i] = valid[i] ? (p[i] + gb) : -INFINITY;

        // batched online softmax update
        float nm = m;
        #pragma unroll
        for (int i = 0; i < 4; i++) nm = fmaxf(nm, gv[i]);
        // guard: all-invalid batch with m still -inf -> exp(nan); force 0
        float sc = (nm == -INFINITY) ? 0.f : __expf(m - nm);
        float e[4];
        #pragma unroll
        for (int i = 0; i < 4; i++)
            e[i] = valid[i] ? __expf(gv[i] - nm) : 0.f;
        m = nm;
        d = d * sc + (e[0] + e[1] + e[2] + e[3]);

        att.x = att.x * sc + e[0]*xr[0].x + e[1]*xr[1].x + e[2]*xr[2].x + e[3]*xr[3].x;
        att.y = att.y * sc + e[0]*xr[0].y + e[1]*xr[1].y + e[2]*xr[2].y + e[3]*xr[3].y;
        att.z = att.z * sc + e[0]*xr[0].z + e[1]*xr[1].z + e[2]*xr[2].z + e[3]*xr[3].z;
        att.w = att.w * sc + e[0]*xr[0].w + e[1]*xr[1].w + e[2]*xr[2].w + e[3]*xr[3].w;

        #pragma unroll
        for (int i = 0; i < 4; i++) {
            sum.x += xr[i].x; sum.y += xr[i].y;
            sum.z += xr[i].z; sum.w += xr[i].w;
            float nx = valid[i] ? xr[i].x : -INFINITY;
            float ny = valid[i] ? xr[i].y : -INFINITY;
            float nz = valid[i] ? xr[i].z : -INFINITY;
            float nw = valid[i] ? xr[i].w : -INFINITY;
            mx.x = fmaxf(mx.x, nx);
            mx.y = fmaxf(mx.y, ny);
            mx.z = fmaxf(mx.z, nz);
            mx.w = fmaxf(mx.w, nw);
        }
    }

    // --- stash per-group partials in LDS ---
    ((float4*)s_att[grp])[lane] = att;
    ((float4*)s_sum[grp])[lane] = sum;
    ((float4*)s_mx[grp])[lane]  = mx;
    if (lane == 0) { s_m[grp] = m; s_d[grp] = d; }
    __syncthreads();

    // --- merge 8 groups; build combined = [att, mean, max] ---
    if (t < H) {
        const int f = t;
        float M = -INFINITY;
        #pragma unroll
        for (int k = 0; k < 8; k++) M = fmaxf(M, s_m[k]);

        float D = 0.f, attf = 0.f, sm = 0.f, mxf = -INFINITY;
        #pragma unroll
        for (int k = 0; k < 8; k++) {
            float w = __expf(s_m[k] - M);   // m=-inf group -> w=0 (cnt>0 case)
            D    += w * s_d[k];
            attf += w * s_att[k][f];
            sm   += s_sum[k][f];
            mxf   = fmaxf(mxf, s_mx[k][f]);
        }

        float o_att, o_mean, o_mx;
        if (cnt > 0) {
            o_att  = attf / fmaxf(D, 1e-16f);
            o_mean = sm / (float)cnt;
            o_mx   = mxf;
        } else {
            o_att = 0.f; o_mean = 0.f; o_mx = 0.f;  // matches isfinite guards
        }
        s_comb[f]         = o_att;
        s_comb[H + f]     = o_mean;
        s_comb[2 * H + f] = o_mx;
    }
    __syncthreads();

    // --- fused combine matmul: out[g,:] = combined @ W + b  (W: [384,128]) ---
    {
        const int j    = t & (H - 1);   // output column
        const int half = t >> 7;        // 0 or 1: split k-range 2-way
        const int k0   = half * 192;
        float acc = 0.f;
        #pragma unroll 8
        for (int k = k0; k < k0 + 192; k++)
            acc += s_comb[k] * combine_w[k * H + j];
        if (half == 0) s_part[j] = acc;
        __syncthreads();
        if (half == 1)
            out[(size_t)g * H + j] = acc + s_part[j] + combine_b[j];
    }
}

extern "C" void kernel_launch(void* const* d_in, const int* in_sizes, int n_in,
                              void* d_out, int out_size, void* d_ws, size_t ws_size,
                              hipStream_t stream) {
    const float* x         = (const float*)d_in[0];
    const int*   batch     = (const int*)d_in[1];
    const float* gate_w    = (const float*)d_in[2];
    const float* gate_b    = (const float*)d_in[3];
    const float* combine_w = (const float*)d_in[4];
    const float* combine_b = (const float*)d_in[5];
    float* out = (float*)d_out;

    const int N = in_sizes[0] / H;
    const int G = out_size / H;

    pool_kernel<<<G, 256, 0, stream>>>(x, batch, gate_w, gate_b,
                                       combine_w, combine_b, out, N);
}